// Round 5
// baseline (489.534 us; speedup 1.0000x reference)
//
#include <hip/hip_runtime.h>

#define D 128
#define TR 64               // tile rows per block
#define BN_EPS 1e-5f
#define SCAN_B 256

typedef __bf16 bf16_t;
typedef __bf16 bf16x8 __attribute__((ext_vector_type(8)));
typedef __bf16 bf16x2 __attribute__((ext_vector_type(2)));
typedef float floatx4 __attribute__((ext_vector_type(4)));

// ===========================================================================
// CSR build phase (scratch aliases into the z buffer)
// ===========================================================================
__global__ void zero_counts(int* __restrict__ counts, float* __restrict__ stats, int n) {
  int i = blockIdx.x * blockDim.x + threadIdx.x;
  if (i < n) counts[i] = 0;
  if (i < 768) stats[i] = 0.f;    // 3 layers x 256 stats
}

__global__ void count_edges(const int* __restrict__ dst, int* __restrict__ counts, int E) {
  int e = blockIdx.x * blockDim.x + threadIdx.x;
  if (e < E) atomicAdd(&counts[dst[e]], 1);
}

__global__ __launch_bounds__(SCAN_B) void scan_blocks(const int* __restrict__ counts,
                                                      int* __restrict__ excl,
                                                      int* __restrict__ blockSums, int n) {
  __shared__ int tmp[SCAN_B];
  int gid = blockIdx.x * SCAN_B + threadIdx.x;
  int v = (gid < n) ? counts[gid] : 0;
  tmp[threadIdx.x] = v;
  __syncthreads();
  for (int off = 1; off < SCAN_B; off <<= 1) {
    int y = (threadIdx.x >= off) ? tmp[threadIdx.x - off] : 0;
    __syncthreads();
    tmp[threadIdx.x] += y;
    __syncthreads();
  }
  if (gid < n) excl[gid] = tmp[threadIdx.x] - v;
  if (threadIdx.x == SCAN_B - 1) blockSums[blockIdx.x] = tmp[SCAN_B - 1];
}

__global__ __launch_bounds__(SCAN_B) void scan_tops(int* __restrict__ blockSums, int nb) {
  __shared__ int tmp[SCAN_B];
  int v = (threadIdx.x < nb) ? blockSums[threadIdx.x] : 0;
  tmp[threadIdx.x] = v;
  __syncthreads();
  for (int off = 1; off < SCAN_B; off <<= 1) {
    int y = (threadIdx.x >= off) ? tmp[threadIdx.x - off] : 0;
    __syncthreads();
    tmp[threadIdx.x] += y;
    __syncthreads();
  }
  if (threadIdx.x < nb) blockSums[threadIdx.x] = tmp[threadIdx.x] - v;
}

__global__ void add_offsets(const int* __restrict__ excl, const int* __restrict__ blockSums,
                            int* __restrict__ row_ptr, int* __restrict__ cursor,
                            int n, int E) {
  int gid = blockIdx.x * blockDim.x + threadIdx.x;
  if (gid < n) {
    int v = excl[gid] + blockSums[gid >> 8];
    row_ptr[gid] = v;
    cursor[gid] = v;
  }
  if (gid == 0) row_ptr[n] = E;
}

__global__ void fill_edges(const int* __restrict__ src, const int* __restrict__ dst,
                           int* __restrict__ cursor, int* __restrict__ col, int E) {
  int e = blockIdx.x * blockDim.x + threadIdx.x;
  if (e < E) {
    int slot = atomicAdd(&cursor[dst[e]], 1);
    col[slot] = src[e];
  }
}

// x (fp32) -> hb (bf16)
__global__ void x2b(const float* __restrict__ x, bf16_t* __restrict__ hb, int n4) {
  int i = blockIdx.x * blockDim.x + threadIdx.x;
  if (i < n4) {
    float4 v = ((const float4*)x)[i];
    bf16x2 p0, p1;
    p0[0] = (bf16_t)v.x; p0[1] = (bf16_t)v.y;
    p1[0] = (bf16_t)v.z; p1[1] = (bf16_t)v.w;
    ((bf16x2*)hb)[2 * i] = p0;
    ((bf16x2*)hb)[2 * i + 1] = p1;
  }
}

// ===========================================================================
// Pre-swizzle weights into MFMA B-fragment order, bf16.
// lane = quad*16 + (n&15) holds B[k = kc*32 + quad*8 + j][n], j=0..7
// Wsw[mat][ ((ntile*4+kc)*64 + lane)*8 + j ]
// ===========================================================================
__global__ void swizzle_weights(const float* __restrict__ W1, const float* __restrict__ W2,
                                bf16_t* __restrict__ Wsw) {
  int i = blockIdx.x * blockDim.x + threadIdx.x;
  if (i >= 6 * 16384) return;
  int mat = i >> 14;
  int kn = i & 16383;
  int k = kn >> 7;
  int n = kn & 127;
  const float* Wm = (mat < 3) ? (W1 + (size_t)mat * 16384) : (W2 + (size_t)(mat - 3) * 16384);
  float v = Wm[kn];
  int f = ((n >> 4) << 2) | (k >> 5);
  int lane = (((k >> 3) & 3) << 4) | (n & 15);
  int j = k & 7;
  Wsw[(size_t)mat * 16384 + ((f << 6) + lane) * 8 + j] = (bf16_t)v;
}

// ===========================================================================
// Kernel A: gather z-tile into LDS (+ write z to global), MFMA w/ W1,
// emit BN column sums/sumsq only (Y is NOT stored — recomputed in kernel C).
// Block 256 = 4 waves; 64 nodes; wave wv handles rows wv*16..wv*16+15.
// ===========================================================================
__global__ __launch_bounds__(256) void agg_gemm1_stats(
    const bf16_t* __restrict__ h, bf16_t* __restrict__ z,
    const int* __restrict__ row_ptr, const int* __restrict__ col,
    const bf16_t* __restrict__ Wsw, const float* __restrict__ bias,
    float* __restrict__ stats, int N) {
  __shared__ bf16_t As[TR][136];     // +8 pad
  __shared__ float sred[256];
  const int t = threadIdx.x;
  const int block_row = blockIdx.x * TR;
  const int wv = t >> 6;
  const int lane = t & 63;

  sred[t] = 0.f;

  // ---- gather phase: z[v] = h[v] + sum h[u] ----
  const int off = lane << 1;
#pragma unroll 1
  for (int i = 0; i < 16; ++i) {
    int r = wv * 16 + i;
    int node = block_row + r;
    float ax = 0.f, ay = 0.f, bx = 0.f, by = 0.f;
    if (node < N) {
      bf16x2 sv = *(const bf16x2*)(h + (size_t)node * D + off);
      ax = (float)sv[0]; ay = (float)sv[1];
      int beg = row_ptr[node];
      int end = row_ptr[node + 1];
      int e = beg;
      for (; e + 2 <= end; e += 2) {
        bf16x2 v0 = *(const bf16x2*)(h + (size_t)col[e] * D + off);
        bf16x2 v1 = *(const bf16x2*)(h + (size_t)col[e + 1] * D + off);
        ax += (float)v0[0]; ay += (float)v0[1];
        bx += (float)v1[0]; by += (float)v1[1];
      }
      if (e < end) {
        bf16x2 v = *(const bf16x2*)(h + (size_t)col[e] * D + off);
        ax += (float)v[0]; ay += (float)v[1];
      }
    }
    ax += bx; ay += by;
    bf16x2 o;
    o[0] = (bf16_t)ax; o[1] = (bf16_t)ay;
    *(bf16x2*)&As[r][off] = o;
    if (node < N) *(bf16x2*)(z + (size_t)node * D + off) = o;
  }
  __syncthreads();

  // ---- MFMA phase ----
  const int l15 = lane & 15;
  const int quad = lane >> 4;

  bf16x8 a[4];
#pragma unroll
  for (int kc = 0; kc < 4; ++kc)
    a[kc] = *(const bf16x8*)&As[wv * 16 + l15][kc * 32 + quad * 8];

  floatx4 acc[8];
#pragma unroll
  for (int nt = 0; nt < 8; ++nt) {
    float bv = bias[nt * 16 + l15];
    acc[nt] = (floatx4){bv, bv, bv, bv};
  }

#pragma unroll
  for (int nt = 0; nt < 8; ++nt) {
#pragma unroll
    for (int kc = 0; kc < 4; ++kc) {
      bf16x8 b = *(const bf16x8*)(Wsw + (size_t)((nt * 4 + kc) * 64 + lane) * 8);
      acc[nt] = __builtin_amdgcn_mfma_f32_16x16x32_bf16(a[kc], b, acc[nt], 0, 0, 0);
    }
  }

  // ---- stats epilogue: C/D layout col = nt*16 + l15, row = quad*4 + r ----
  const int rowBase = block_row + wv * 16 + quad * 4;
#pragma unroll
  for (int nt = 0; nt < 8; ++nt) {
    int c = nt * 16 + l15;
    float s = 0.f, q = 0.f;
#pragma unroll
    for (int r = 0; r < 4; ++r) {
      if (rowBase + r < N) {
        float v = acc[nt][r];
        s += v; q += v * v;
      }
    }
    s += __shfl_xor(s, 16); s += __shfl_xor(s, 32);
    q += __shfl_xor(q, 16); q += __shfl_xor(q, 32);
    if (quad == 0) {
      atomicAdd(&sred[c], s);
      atomicAdd(&sred[128 + c], q);
    }
  }
  __syncthreads();
  atomicAdd(&stats[t], sred[t]);
}

// ===========================================================================
// Kernel C: a,b from stats (folded bn_finalize) -> recompute Y = Z@W1+b1
// (bit-identical to kernel A) -> BN+ReLU in regs -> LDS relayout ->
// GEMM2 -> maybe_relu -> h' (bf16) or out (fp32).
// ===========================================================================
__global__ __launch_bounds__(256) void fused_mlp(
    const bf16_t* __restrict__ Z, const float* __restrict__ stats,
    const float* __restrict__ gamma, const float* __restrict__ beta,
    const bf16_t* __restrict__ W1sw, const float* __restrict__ b1,
    const bf16_t* __restrict__ W2sw, const float* __restrict__ b2,
    void* __restrict__ outp, int N, float invN, int relu_out, int fp32_out) {
  __shared__ bf16_t As[TR][136];
  __shared__ float abL[256];
  const int t = threadIdx.x;
  const int block_row = blockIdx.x * TR;

  // bn coefficients (redundant per block; ~256 B of L2-hot loads)
  if (t < 128) {
    float mu = stats[t] * invN;
    float var = fmaxf(stats[128 + t] * invN - mu * mu, 0.f);
    float a = gamma[t] * rsqrtf(var + BN_EPS);
    abL[t] = a;
    abL[128 + t] = beta[t] - mu * a;
  }

  // stage Z tile (16B copies)
  for (int i = t; i < TR * 16; i += 256) {
    int r = i >> 4;
    int c = (i & 15) << 3;
    int gr = block_row + r;
    uint4 v = make_uint4(0, 0, 0, 0);
    if (gr < N) v = *(const uint4*)(Z + (size_t)gr * D + c);
    *(uint4*)&As[r][c] = v;
  }
  __syncthreads();

  const int wv = t >> 6;
  const int lane = t & 63;
  const int l15 = lane & 15;
  const int quad = lane >> 4;

  bf16x8 a[4];
#pragma unroll
  for (int kc = 0; kc < 4; ++kc)
    a[kc] = *(const bf16x8*)&As[wv * 16 + l15][kc * 32 + quad * 8];

  float ar[8], br[8];
#pragma unroll
  for (int nt = 0; nt < 8; ++nt) {
    ar[nt] = abL[nt * 16 + l15];
    br[nt] = abL[128 + nt * 16 + l15];
  }

  floatx4 acc[8];
#pragma unroll
  for (int nt = 0; nt < 8; ++nt) {
    float bv = b1[nt * 16 + l15];
    acc[nt] = (floatx4){bv, bv, bv, bv};
  }

  __syncthreads();   // all waves' frag/coeff reads from LDS done

#pragma unroll
  for (int nt = 0; nt < 8; ++nt) {
#pragma unroll
    for (int kc = 0; kc < 4; ++kc) {
      bf16x8 b = *(const bf16x8*)(W1sw + (size_t)((nt * 4 + kc) * 64 + lane) * 8);
      acc[nt] = __builtin_amdgcn_mfma_f32_16x16x32_bf16(a[kc], b, acc[nt], 0, 0, 0);
    }
  }

  // BN + ReLU, write P-tile into LDS at C-layout positions (bf16)
  const int lr = wv * 16 + quad * 4;   // local row base
#pragma unroll
  for (int nt = 0; nt < 8; ++nt) {
    int c = nt * 16 + l15;
#pragma unroll
    for (int r = 0; r < 4; ++r) {
      float v = fmaxf(fmaf(acc[nt][r], ar[nt], br[nt]), 0.f);
      As[lr + r][c] = (bf16_t)v;
    }
  }
  __syncthreads();

  // GEMM2
  bf16x8 a2[4];
#pragma unroll
  for (int kc = 0; kc < 4; ++kc)
    a2[kc] = *(const bf16x8*)&As[wv * 16 + l15][kc * 32 + quad * 8];

  floatx4 acc2[8];
#pragma unroll
  for (int nt = 0; nt < 8; ++nt) {
    float bv = b2[nt * 16 + l15];
    acc2[nt] = (floatx4){bv, bv, bv, bv};
  }

#pragma unroll
  for (int nt = 0; nt < 8; ++nt) {
#pragma unroll
    for (int kc = 0; kc < 4; ++kc) {
      bf16x8 b = *(const bf16x8*)(W2sw + (size_t)((nt * 4 + kc) * 64 + lane) * 8);
      acc2[nt] = __builtin_amdgcn_mfma_f32_16x16x32_bf16(a2[kc], b, acc2[nt], 0, 0, 0);
    }
  }

  const int rowBase = block_row + wv * 16 + quad * 4;
  if (fp32_out) {
    float* out = (float*)outp;
#pragma unroll
    for (int nt = 0; nt < 8; ++nt) {
      int c = nt * 16 + l15;
#pragma unroll
      for (int r = 0; r < 4; ++r) {
        int row = rowBase + r;
        if (row < N) {
          float v = acc2[nt][r];
          if (relu_out) v = fmaxf(v, 0.f);
          out[(size_t)row * D + c] = v;
        }
      }
    }
  } else {
    bf16_t* out = (bf16_t*)outp;
#pragma unroll
    for (int nt = 0; nt < 8; ++nt) {
      int c = nt * 16 + l15;
#pragma unroll
      for (int r = 0; r < 4; ++r) {
        int row = rowBase + r;
        if (row < N) {
          float v = acc2[nt][r];
          if (relu_out) v = fmaxf(v, 0.f);
          out[(size_t)row * D + c] = (bf16_t)v;
        }
      }
    }
  }
}

// ===========================================================================
extern "C" void kernel_launch(void* const* d_in, const int* in_sizes, int n_in,
                              void* d_out, int out_size, void* d_ws, size_t ws_size,
                              hipStream_t stream) {
  const float* x     = (const float*)d_in[0];
  const float* W1    = (const float*)d_in[1];
  const float* b1    = (const float*)d_in[2];
  const float* gamma = (const float*)d_in[3];
  const float* beta  = (const float*)d_in[4];
  const float* W2    = (const float*)d_in[5];
  const float* b2    = (const float*)d_in[6];
  const int*   ei    = (const int*)d_in[7];

  const int N = in_sizes[0] / D;
  const int E = in_sizes[7] / 2;
  const int* src = ei;
  const int* dst = ei + E;

  char* ws = (char*)d_ws;
  size_t bufBytes = (size_t)N * D * sizeof(bf16_t);   // 12.8 MB
  bf16_t* hb   = (bf16_t*)ws;                          // persistent h (bf16)
  bf16_t* zb   = (bf16_t*)(ws + bufBytes);             // agg output
  float* stats = (float*)(ws + 2 * bufBytes);          // 3 x 256 floats
  bf16_t* Wsw  = (bf16_t*)(ws + 2 * bufBytes + 4096);  // 6*16384 bf16
  int* row_ptr = (int*)(ws + 2 * bufBytes + 4096 + 6 * 16384 * sizeof(bf16_t));
  int* col     = row_ptr + (N + 1);
  // build-phase scratch aliases zb (dead until layer-0 kernel A writes it)
  int* counts    = (int*)zb;
  int* excl      = counts + N;
  int* cursor    = excl + N;
  int* blockSums = cursor + N;

  const int nb = (N + SCAN_B - 1) / SCAN_B;
  const int eb = (E + 255) / 256;
  const int tileBlocks = (N + TR - 1) / TR;
  const int n4 = N * D / 4;
  const float invN = 1.f / (float)N;

  // ---- CSR build + conversions ----
  zero_counts<<<(N + 255) / 256, 256, 0, stream>>>(counts, stats, N);
  count_edges<<<eb, 256, 0, stream>>>(dst, counts, E);
  x2b<<<(n4 + 255) / 256, 256, 0, stream>>>(x, hb, n4);
  swizzle_weights<<<(6 * 16384 + 255) / 256, 256, 0, stream>>>(W1, W2, Wsw);
  scan_blocks<<<nb, SCAN_B, 0, stream>>>(counts, excl, blockSums, N);
  scan_tops<<<1, SCAN_B, 0, stream>>>(blockSums, nb);
  add_offsets<<<(N + 255) / 256, 256, 0, stream>>>(excl, blockSums, row_ptr, cursor, N, E);
  fill_edges<<<eb, 256, 0, stream>>>(src, dst, cursor, col, E);

  // ---- layers: 2 dispatches each ----
  for (int i = 0; i < 3; ++i) {
    float* st = stats + (size_t)i * 256;
    agg_gemm1_stats<<<tileBlocks, 256, 0, stream>>>(
        hb, zb, row_ptr, col, Wsw + (size_t)i * 16384, b1 + (size_t)i * D, st, N);
    void* Ob = (i == 2) ? d_out : (void*)hb;
    fused_mlp<<<tileBlocks, 256, 0, stream>>>(
        zb, st, gamma + (size_t)i * D, beta + (size_t)i * D,
        Wsw + (size_t)i * 16384, b1 + (size_t)i * D,
        Wsw + (size_t)(i + 3) * 16384, b2 + (size_t)i * D,
        Ob, N, invN, (i < 2) ? 1 : 0, (i == 2) ? 1 : 0);
  }
}

// Round 6
// 375.363 us; speedup vs baseline: 1.3042x; 1.3042x over previous
//
#include <hip/hip_runtime.h>

#define D 128
#define BN_EPS 1e-5f
#define SCAN_B 256

typedef __bf16 bf16_t;
typedef __bf16 bf16x8 __attribute__((ext_vector_type(8)));
typedef __bf16 bf16x2 __attribute__((ext_vector_type(2)));
typedef float floatx4 __attribute__((ext_vector_type(4)));

// ===========================================================================
// prep: zero counts[N] + stats[768], x fp32 -> hb bf16, swizzle weights
// grid covers n4 = N*D/4 elements (largest range)
// ===========================================================================
__global__ void prep(const float* __restrict__ x, bf16_t* __restrict__ hb,
                     const float* __restrict__ W1, const float* __restrict__ W2,
                     bf16_t* __restrict__ Wsw, int* __restrict__ counts,
                     float* __restrict__ stats, int N, int n4) {
  int i = blockIdx.x * blockDim.x + threadIdx.x;
  if (i < n4) {
    float4 v = ((const float4*)x)[i];
    bf16x2 p0, p1;
    p0[0] = (bf16_t)v.x; p0[1] = (bf16_t)v.y;
    p1[0] = (bf16_t)v.z; p1[1] = (bf16_t)v.w;
    ((bf16x2*)hb)[2 * i] = p0;
    ((bf16x2*)hb)[2 * i + 1] = p1;
  }
  if (i < N) counts[i] = 0;
  if (i < 768) stats[i] = 0.f;
  if (i < 6 * 16384) {
    // B-frag order: lane = quad*16 + (n&15) holds B[k=kc*32+quad*8+j][n]
    int mat = i >> 14;
    int kn = i & 16383;
    int k = kn >> 7;
    int n = kn & 127;
    const float* Wm = (mat < 3) ? (W1 + (size_t)mat * 16384)
                                : (W2 + (size_t)(mat - 3) * 16384);
    float v = Wm[kn];
    int f = ((n >> 4) << 2) | (k >> 5);
    int lane = (((k >> 3) & 3) << 4) | (n & 15);
    int j = k & 7;
    Wsw[(size_t)mat * 16384 + ((f << 6) + lane) * 8 + j] = (bf16_t)v;
  }
}

// ===========================================================================
// CSR build
// ===========================================================================
__global__ void count_edges(const int* __restrict__ dst, int* __restrict__ counts, int E) {
  int e = blockIdx.x * blockDim.x + threadIdx.x;
  if (e < E) atomicAdd(&counts[dst[e]], 1);
}

__global__ __launch_bounds__(SCAN_B) void scan_blocks(const int* __restrict__ counts,
                                                      int* __restrict__ excl,
                                                      int* __restrict__ blockSums, int n) {
  __shared__ int tmp[SCAN_B];
  int gid = blockIdx.x * SCAN_B + threadIdx.x;
  int v = (gid < n) ? counts[gid] : 0;
  tmp[threadIdx.x] = v;
  __syncthreads();
  for (int off = 1; off < SCAN_B; off <<= 1) {
    int y = (threadIdx.x >= off) ? tmp[threadIdx.x - off] : 0;
    __syncthreads();
    tmp[threadIdx.x] += y;
    __syncthreads();
  }
  if (gid < n) excl[gid] = tmp[threadIdx.x] - v;
  if (threadIdx.x == SCAN_B - 1) blockSums[blockIdx.x] = tmp[SCAN_B - 1];
}

__global__ __launch_bounds__(SCAN_B) void scan_tops(int* __restrict__ blockSums, int nb) {
  __shared__ int tmp[SCAN_B];
  int v = (threadIdx.x < nb) ? blockSums[threadIdx.x] : 0;
  tmp[threadIdx.x] = v;
  __syncthreads();
  for (int off = 1; off < SCAN_B; off <<= 1) {
    int y = (threadIdx.x >= off) ? tmp[threadIdx.x - off] : 0;
    __syncthreads();
    tmp[threadIdx.x] += y;
    __syncthreads();
  }
  if (threadIdx.x < nb) blockSums[threadIdx.x] = tmp[threadIdx.x] - v;
}

__global__ void add_offsets(const int* __restrict__ excl, const int* __restrict__ blockSums,
                            int* __restrict__ row_ptr, int* __restrict__ cursor,
                            int n, int E) {
  int gid = blockIdx.x * blockDim.x + threadIdx.x;
  if (gid < n) {
    int v = excl[gid] + blockSums[gid >> 8];
    row_ptr[gid] = v;
    cursor[gid] = v;
  }
  if (gid == 0) row_ptr[n] = E;
}

__global__ void fill_edges(const int* __restrict__ src, const int* __restrict__ dst,
                           int* __restrict__ cursor, int* __restrict__ col, int E) {
  int e = blockIdx.x * blockDim.x + threadIdx.x;
  if (e < E) {
    int slot = atomicAdd(&cursor[dst[e]], 1);
    col[slot] = src[e];
  }
}

// ===========================================================================
// aggregate: z[v] = h[v] + sum_{u in N(v)} h[u] — one wave per node,
// bf16x2 per lane, fp32 accum, 4-wide edge unroll for MLP.
// ===========================================================================
__global__ __launch_bounds__(256) void aggregate(const bf16_t* __restrict__ h,
                                                 bf16_t* __restrict__ z,
                                                 const int* __restrict__ row_ptr,
                                                 const int* __restrict__ col, int Nn) {
  int node = blockIdx.x * 4 + (threadIdx.x >> 6);
  if (node >= Nn) return;
  int lane = threadIdx.x & 63;
  int off = lane << 1;
  int beg = row_ptr[node];
  int end = row_ptr[node + 1];

  bf16x2 sv = *(const bf16x2*)(h + (size_t)node * D + off);
  float a0x = (float)sv[0], a0y = (float)sv[1];
  float a1x = 0.f, a1y = 0.f, a2x = 0.f, a2y = 0.f, a3x = 0.f, a3y = 0.f;
  int e = beg;
  for (; e + 4 <= end; e += 4) {
    bf16x2 v0 = *(const bf16x2*)(h + (size_t)col[e] * D + off);
    bf16x2 v1 = *(const bf16x2*)(h + (size_t)col[e + 1] * D + off);
    bf16x2 v2 = *(const bf16x2*)(h + (size_t)col[e + 2] * D + off);
    bf16x2 v3 = *(const bf16x2*)(h + (size_t)col[e + 3] * D + off);
    a0x += (float)v0[0]; a0y += (float)v0[1];
    a1x += (float)v1[0]; a1y += (float)v1[1];
    a2x += (float)v2[0]; a2y += (float)v2[1];
    a3x += (float)v3[0]; a3y += (float)v3[1];
  }
  for (; e < end; ++e) {
    bf16x2 v = *(const bf16x2*)(h + (size_t)col[e] * D + off);
    a0x += (float)v[0]; a0y += (float)v[1];
  }
  a0x += a1x + a2x + a3x;
  a0y += a1y + a2y + a3y;
  bf16x2 o;
  o[0] = (bf16_t)a0x; o[1] = (bf16_t)a0y;
  *(bf16x2*)(z + (size_t)node * D + off) = o;
}

// ===========================================================================
// gemm1_stats: Y = Z @ W1 + b1 (bf16 MFMA). Z A-frags loaded DIRECTLY from
// global (row-major bf16 == A-frag order). Emits BN column sums/sumsq and
// stores Y bf16 in A-fragment-ready order for mlp2 (LDS transpose).
// Block 256 = 4 waves; wave = one 16-row strip.
// ===========================================================================
__global__ __launch_bounds__(256) void gemm1_stats(
    const bf16_t* __restrict__ Z, const bf16_t* __restrict__ Wsw,
    const float* __restrict__ bias, bf16_t* __restrict__ Yf,
    float* __restrict__ stats, int nStrips, int N) {
  __shared__ bf16_t T[64][136];
  __shared__ float sred[256];
  const int t = threadIdx.x;
  const int wv = t >> 6;
  const int lane = t & 63;
  const int l15 = lane & 15;
  const int quad = lane >> 4;
  const int strip = blockIdx.x * 4 + wv;
  const bool active = strip < nStrips;

  sred[t] = 0.f;

  // A-frags direct from global: row = strip*16 + l15, k = kc*32 + quad*8 + j
  bf16x8 a[4];
  const int row = strip * 16 + l15;
  if (active && row < N) {
#pragma unroll
    for (int kc = 0; kc < 4; ++kc)
      a[kc] = *(const bf16x8*)(Z + (size_t)row * D + kc * 32 + quad * 8);
  } else {
#pragma unroll
    for (int kc = 0; kc < 4; ++kc)
#pragma unroll
      for (int j = 0; j < 8; ++j) a[kc][j] = (bf16_t)0.f;
  }

  floatx4 acc[8];
#pragma unroll
  for (int nt = 0; nt < 8; ++nt) {
    float bv = bias[nt * 16 + l15];
    acc[nt] = (floatx4){bv, bv, bv, bv};
  }

#pragma unroll
  for (int nt = 0; nt < 8; ++nt) {
#pragma unroll
    for (int kc = 0; kc < 4; ++kc) {
      bf16x8 b = *(const bf16x8*)(Wsw + (size_t)((nt * 4 + kc) * 64 + lane) * 8);
      acc[nt] = __builtin_amdgcn_mfma_f32_16x16x32_bf16(a[kc], b, acc[nt], 0, 0, 0);
    }
  }

  // transpose C-layout -> A-frag order via LDS (wave-private rows)
  const int lr = wv * 16 + quad * 4;
#pragma unroll
  for (int nt = 0; nt < 8; ++nt) {
    int c = nt * 16 + l15;
#pragma unroll
    for (int r = 0; r < 4; ++r) T[lr + r][c] = (bf16_t)acc[nt][r];
  }
  __syncthreads();
  if (active) {
#pragma unroll
    for (int kc = 0; kc < 4; ++kc) {
      bf16x8 yv = *(const bf16x8*)&T[wv * 16 + l15][kc * 32 + quad * 8];
      *(bf16x8*)(Yf + ((size_t)(strip * 4 + kc) * 64 + lane) * 8) = yv;
    }
  }

  // BN stats: C/D layout col = nt*16+l15, row(strip-local) = quad*4+r
  const int rowBase = strip * 16 + quad * 4;
#pragma unroll
  for (int nt = 0; nt < 8; ++nt) {
    int c = nt * 16 + l15;
    float s = 0.f, q = 0.f;
    if (active) {
#pragma unroll
      for (int r = 0; r < 4; ++r) {
        if (rowBase + r < N) {
          float v = acc[nt][r];
          s += v; q += v * v;
        }
      }
    }
    s += __shfl_xor(s, 16); s += __shfl_xor(s, 32);
    q += __shfl_xor(q, 16); q += __shfl_xor(q, 32);
    if (quad == 0) {
      atomicAdd(&sred[c], s);
      atomicAdd(&sred[128 + c], q);
    }
  }
  __syncthreads();
  atomicAdd(&stats[t], sred[t]);
}

// ===========================================================================
// mlp2: a,b from stats -> load Y A-frags from global -> BN+ReLU elementwise
// in-fragment (BN is per-column; no relayout needed) -> GEMM2 -> store.
// ===========================================================================
__global__ __launch_bounds__(256) void mlp2(
    const bf16_t* __restrict__ Yf, const float* __restrict__ stats,
    const float* __restrict__ gamma, const float* __restrict__ beta,
    const bf16_t* __restrict__ Wsw, const float* __restrict__ bias,
    void* __restrict__ outp, int nStrips, int N, float invN,
    int relu_out, int fp32_out) {
  __shared__ float abL[256];
  const int t = threadIdx.x;
  if (t < 128) {
    float mu = stats[t] * invN;
    float var = fmaxf(stats[128 + t] * invN - mu * mu, 0.f);
    float a = gamma[t] * rsqrtf(var + BN_EPS);
    abL[t] = a;
    abL[128 + t] = beta[t] - mu * a;
  }
  __syncthreads();

  const int wv = t >> 6;
  const int lane = t & 63;
  const int l15 = lane & 15;
  const int quad = lane >> 4;
  const int strip = blockIdx.x * 4 + wv;
  if (strip >= nStrips) return;

  // P = relu(Y*a + b) in A-frag layout: element j of chunk kc has
  // column c = kc*32 + quad*8 + j
  bf16x8 a2[4];
#pragma unroll
  for (int kc = 0; kc < 4; ++kc) {
    bf16x8 y = *(const bf16x8*)(Yf + ((size_t)(strip * 4 + kc) * 64 + lane) * 8);
#pragma unroll
    for (int j = 0; j < 8; ++j) {
      int c = kc * 32 + quad * 8 + j;
      float v = fmaxf(fmaf((float)y[j], abL[c], abL[128 + c]), 0.f);
      a2[kc][j] = (bf16_t)v;
    }
  }

  floatx4 acc[8];
#pragma unroll
  for (int nt = 0; nt < 8; ++nt) {
    float bv = bias[nt * 16 + l15];
    acc[nt] = (floatx4){bv, bv, bv, bv};
  }

#pragma unroll
  for (int nt = 0; nt < 8; ++nt) {
#pragma unroll
    for (int kc = 0; kc < 4; ++kc) {
      bf16x8 b = *(const bf16x8*)(Wsw + (size_t)((nt * 4 + kc) * 64 + lane) * 8);
      acc[nt] = __builtin_amdgcn_mfma_f32_16x16x32_bf16(a2[kc], b, acc[nt], 0, 0, 0);
    }
  }

  const int rowBase = strip * 16 + quad * 4;
  if (fp32_out) {
    float* out = (float*)outp;
#pragma unroll
    for (int nt = 0; nt < 8; ++nt) {
      int c = nt * 16 + l15;
#pragma unroll
      for (int r = 0; r < 4; ++r) {
        int row = rowBase + r;
        if (row < N) {
          float v = acc[nt][r];
          if (relu_out) v = fmaxf(v, 0.f);
          out[(size_t)row * D + c] = v;
        }
      }
    }
  } else {
    bf16_t* out = (bf16_t*)outp;
#pragma unroll
    for (int nt = 0; nt < 8; ++nt) {
      int c = nt * 16 + l15;
#pragma unroll
      for (int r = 0; r < 4; ++r) {
        int row = rowBase + r;
        if (row < N) {
          float v = acc[nt][r];
          if (relu_out) v = fmaxf(v, 0.f);
          out[(size_t)row * D + c] = (bf16_t)v;
        }
      }
    }
  }
}

// ===========================================================================
extern "C" void kernel_launch(void* const* d_in, const int* in_sizes, int n_in,
                              void* d_out, int out_size, void* d_ws, size_t ws_size,
                              hipStream_t stream) {
  const float* x     = (const float*)d_in[0];
  const float* W1    = (const float*)d_in[1];
  const float* b1    = (const float*)d_in[2];
  const float* gamma = (const float*)d_in[3];
  const float* beta  = (const float*)d_in[4];
  const float* W2    = (const float*)d_in[5];
  const float* b2    = (const float*)d_in[6];
  const int*   ei    = (const int*)d_in[7];

  const int N = in_sizes[0] / D;
  const int E = in_sizes[7] / 2;
  const int* src = ei;
  const int* dst = ei + E;

  char* ws = (char*)d_ws;
  size_t bufBytes = (size_t)N * D * sizeof(bf16_t);   // 12.8 MB
  bf16_t* hb   = (bf16_t*)ws;                          // persistent h (bf16)
  bf16_t* zb   = (bf16_t*)(ws + bufBytes);             // agg output
  bf16_t* Yf   = (bf16_t*)(ws + 2 * bufBytes);         // Y in A-frag order
  float* stats = (float*)(ws + 3 * bufBytes);          // 3 x 256 floats
  bf16_t* Wsw  = (bf16_t*)(ws + 3 * bufBytes + 4096);  // 6*16384 bf16
  int* row_ptr = (int*)(ws + 3 * bufBytes + 4096 + 6 * 16384 * sizeof(bf16_t));
  int* col     = row_ptr + (N + 1);
  // build-phase scratch aliases zb (dead until layer-0 aggregate writes it)
  int* counts    = (int*)zb;
  int* excl      = counts + N;
  int* cursor    = excl + N;
  int* blockSums = cursor + N;

  const int nb = (N + SCAN_B - 1) / SCAN_B;
  const int eb = (E + 255) / 256;
  const int aggBlocks = (N + 3) / 4;
  const int nStrips = (N + 15) / 16;
  const int gemmBlocks = (nStrips + 3) / 4;
  const int n4 = N * D / 4;
  const float invN = 1.f / (float)N;

  // ---- prep + CSR build ----
  prep<<<(n4 + 255) / 256, 256, 0, stream>>>(x, hb, W1, W2, Wsw, counts, stats, N, n4);
  count_edges<<<eb, 256, 0, stream>>>(dst, counts, E);
  scan_blocks<<<nb, SCAN_B, 0, stream>>>(counts, excl, blockSums, N);
  scan_tops<<<1, SCAN_B, 0, stream>>>(blockSums, nb);
  add_offsets<<<(N + 255) / 256, 256, 0, stream>>>(excl, blockSums, row_ptr, cursor, N, E);
  fill_edges<<<eb, 256, 0, stream>>>(src, dst, cursor, col, E);

  // ---- layers: 3 dispatches each ----
  for (int i = 0; i < 3; ++i) {
    float* st = stats + (size_t)i * 256;
    aggregate<<<aggBlocks, 256, 0, stream>>>(hb, zb, row_ptr, col, N);
    gemm1_stats<<<gemmBlocks, 256, 0, stream>>>(
        zb, Wsw + (size_t)i * 16384, b1 + (size_t)i * D, Yf, st, nStrips, N);
    void* Ob = (i == 2) ? d_out : (void*)hb;
    mlp2<<<gemmBlocks, 256, 0, stream>>>(
        Yf, st, gamma + (size_t)i * D, beta + (size_t)i * D,
        Wsw + (size_t)(i + 3) * 16384, b2 + (size_t)i * D,
        Ob, nStrips, N, invN, (i < 2) ? 1 : 0, (i == 2) ? 1 : 0);
  }
}